// Round 3
// baseline (2090.668 us; speedup 1.0000x reference)
//
#include <hip/hip_runtime.h>

typedef float f32x4 __attribute__((ext_vector_type(4)));
typedef __bf16 bf16x8 __attribute__((ext_vector_type(8)));

#define NROWS 16384   // B*S
#define SEQ   4096
#define EMBD  512
#define MLPD  2048

__device__ inline float gelu_tanh(float x) {
    float t = 0.7978845608028654f * (x + 0.044715f * x * x * x);
    float e = __expf(2.f * t);
    float th = 1.f - 2.f / (1.f + e);
    return 0.5f * x * (1.f + th);
}

// direct global->LDS 16B DMA; LDS dest must be linear in lane order
#define GLOAD16(gp, lp)                                                        \
    __builtin_amdgcn_global_load_lds(                                          \
        (const __attribute__((address_space(1))) void*)(gp),                   \
        (__attribute__((address_space(3))) void*)(lp), 16, 0, 0)

// ---------------- positional table: pos[s][512] ----------------
__global__ void pos_kernel(float* __restrict__ pos) {
    int i = blockIdx.x * 256 + threadIdx.x;        // 4096*256
    int s = i >> 8, j = i & 255;
    float div = __expf((float)j * (-2.f * 9.210340371976184f / 512.f));
    float a = (float)s * div;
    pos[(size_t)s * 512 + 2 * j]     = sinf(a);
    pos[(size_t)s * 512 + 2 * j + 1] = cosf(a);
}

// ---------------- embedding gather + pos add ----------------
__global__ void embed_kernel(const int* __restrict__ tokens,
                             const float* __restrict__ embed,
                             const float* __restrict__ pos,
                             float* __restrict__ x) {
    int row = blockIdx.x;            // 16384
    int t = threadIdx.x;             // 128
    int s = row & (SEQ - 1);
    int tok = tokens[row];
    f32x4 e = *(const f32x4*)(embed + (size_t)tok * 512 + t * 4);
    f32x4 p = *(const f32x4*)(pos + (size_t)s * 512 + t * 4);
    e += p;
    *(f32x4*)(x + (size_t)row * 512 + t * 4) = e;
}

// ---------------- transpose fp32 [K][N] -> bf16 [N][K], batched over z ----------------
__global__ void transpose_bf16(const float* __restrict__ in, __bf16* __restrict__ out,
                               int K, int N, size_t in_lstride, size_t out_lstride) {
    __shared__ float tile[32][33];
    in  += (size_t)blockIdx.z * in_lstride;
    out += (size_t)blockIdx.z * out_lstride;
    int n0 = blockIdx.x * 32, k0 = blockIdx.y * 32;
    int tx = threadIdx.x, ty = threadIdx.y;   // 32 x 8
    #pragma unroll
    for (int i = 0; i < 32; i += 8)
        tile[ty + i][tx] = in[(size_t)(k0 + ty + i) * N + n0 + tx];
    __syncthreads();
    #pragma unroll
    for (int i = 0; i < 32; i += 8)
        out[(size_t)(n0 + ty + i) * K + k0 + tx] = (__bf16)tile[tx][ty + i];
}

// ---------------- LayerNorm (one wave per 512-row) ----------------
template<int OUTBF>
__global__ __launch_bounds__(256) void ln_kernel(
    const float* __restrict__ x, const float* __restrict__ gamma,
    const float* __restrict__ beta, __bf16* __restrict__ outb,
    float* __restrict__ outf) {
    int lane = threadIdx.x & 63;
    size_t row = (size_t)blockIdx.x * 4 + (threadIdx.x >> 6);
    const float* xr = x + row * 512 + lane * 8;
    f32x4 v0 = *(const f32x4*)xr;
    f32x4 v1 = *(const f32x4*)(xr + 4);
    float sum = (v0[0] + v0[1]) + (v0[2] + v0[3]) + (v1[0] + v1[1]) + (v1[2] + v1[3]);
    #pragma unroll
    for (int off = 32; off; off >>= 1) sum += __shfl_xor(sum, off);
    float mu = sum * (1.f / 512.f);
    float vs = 0.f;
    #pragma unroll
    for (int j = 0; j < 4; j++) {
        float d0 = v0[j] - mu; vs += d0 * d0;
        float d1 = v1[j] - mu; vs += d1 * d1;
    }
    #pragma unroll
    for (int off = 32; off; off >>= 1) vs += __shfl_xor(vs, off);
    float inv = rsqrtf(vs * (1.f / 512.f) + 1e-6f);
    const float* gp = gamma + lane * 8;
    const float* bp = beta + lane * 8;
    f32x4 g0 = *(const f32x4*)gp, g1 = *(const f32x4*)(gp + 4);
    f32x4 bb0 = *(const f32x4*)bp, bb1 = *(const f32x4*)(bp + 4);
    float o[8];
    #pragma unroll
    for (int j = 0; j < 4; j++) {
        o[j]     = (v0[j] - mu) * inv * g0[j] + bb0[j];
        o[4 + j] = (v1[j] - mu) * inv * g1[j] + bb1[j];
    }
    if (OUTBF) {
        bf16x8 ov;
        #pragma unroll
        for (int j = 0; j < 8; j++) ov[j] = (__bf16)o[j];
        *(bf16x8*)(outb + row * 512 + lane * 8) = ov;
    } else {
        f32x4 o0 = {o[0], o[1], o[2], o[3]};
        f32x4 o1 = {o[4], o[5], o[6], o[7]};
        *(f32x4*)(outf + row * 512 + lane * 8) = o0;
        *(f32x4*)(outf + row * 512 + lane * 8 + 4) = o1;
    }
}

// ---------------- MFMA GEMM: C[M,N] = A[M,K](bf16) @ BT[N,K](bf16) ----------------
// BK=64, double-buffered LDS, counted vmcnt(8) + raw s_barrier: next tile's
// global_load_lds stay in flight across the barrier (T3/T4 minimum form).
// LDS layout: per row 8 chunks of 16B, chunk XOR-swizzled with (row&7);
// staged via linear LDS dest + pre-swizzled global source (rule #21).
// EPI: 1 = qkv (phi on cols<1024, fp32 out ld=N)
//      2 = residual add into Cf
//      3 = +bias, gelu, bf16 out
//      4 = +bias, residual add into Cf
template<int EPI, int K>
__global__ __launch_bounds__(256) void gemm_bt(
    const __bf16* __restrict__ A, const __bf16* __restrict__ BT,
    float* __restrict__ Cf, __bf16* __restrict__ Cb,
    const float* __restrict__ bias, int N) {
    constexpr int NS = K / 64;
    __shared__ __align__(16) __bf16 Abuf[2][128 * 64];
    __shared__ __align__(16) __bf16 Bbuf[2][128 * 64];
    const int t = threadIdx.x;
    const int lane = t & 63;
    const int wave = t >> 6;
    const int wr = wave >> 1, wc = wave & 1;
    const int m0 = blockIdx.x * 128, n0 = blockIdx.y * 128;
    const int fr = lane & 15, fc = lane >> 4;

    // staging: thread t fills 16B-slots {t, t+256, t+512, t+768} of each buffer
    const __bf16* Aps[4];
    const __bf16* Bps[4];
    int lslot[4];
    #pragma unroll
    for (int j = 0; j < 4; j++) {
        int slot = t + 256 * j;
        int row = slot >> 3, cp = slot & 7;
        int sc = cp ^ (row & 7);               // pre-swizzled source chunk
        Aps[j] = A  + (size_t)(m0 + row) * K + sc * 8;
        Bps[j] = BT + (size_t)(n0 + row) * K + sc * 8;
        lslot[j] = slot * 8;                    // elem offset (16B slots)
    }

    f32x4 acc[4][4];
    #pragma unroll
    for (int m = 0; m < 4; m++)
        #pragma unroll
        for (int n = 0; n < 4; n++)
            acc[m][n] = (f32x4){0.f, 0.f, 0.f, 0.f};

    auto stage = [&](int koff, __bf16* Ad, __bf16* Bd) {
        #pragma unroll
        for (int j = 0; j < 4; j++) GLOAD16(Aps[j] + koff, Ad + lslot[j]);
        #pragma unroll
        for (int j = 0; j < 4; j++) GLOAD16(Bps[j] + koff, Bd + lslot[j]);
    };

    __bf16* Ac = Abuf[0]; __bf16* An = Abuf[1];
    __bf16* Bc = Bbuf[0]; __bf16* Bn = Bbuf[1];
    stage(0, Ac, Bc);

    for (int s = 0; s < NS; s++) {
        if (s + 1 < NS) {
            stage((s + 1) * 64, An, Bn);
            asm volatile("s_waitcnt vmcnt(8)" ::: "memory");   // cur tile done, next in flight
        } else {
            asm volatile("s_waitcnt vmcnt(0)" ::: "memory");
        }
        __builtin_amdgcn_s_barrier();

        bf16x8 af[2][4], bfr[2][4];
        #pragma unroll
        for (int kk = 0; kk < 2; kk++) {
            #pragma unroll
            for (int m = 0; m < 4; m++) {
                int ra = wr * 64 + m * 16 + fr;
                int rb = wc * 64 + m * 16 + fr;
                int c = kk * 4 + fc;
                af[kk][m]  = *(const bf16x8*)(Ac + ra * 64 + ((c ^ (ra & 7)) << 3));
                bfr[kk][m] = *(const bf16x8*)(Bc + rb * 64 + ((c ^ (rb & 7)) << 3));
            }
        }
        #pragma unroll
        for (int kk = 0; kk < 2; kk++)
            #pragma unroll
            for (int m = 0; m < 4; m++)
                #pragma unroll
                for (int n = 0; n < 4; n++)
                    acc[m][n] = __builtin_amdgcn_mfma_f32_16x16x32_bf16(af[kk][m], bfr[kk][n], acc[m][n], 0, 0, 0);

        __builtin_amdgcn_s_barrier();   // readers done before next stage overwrites
        __bf16* tp;
        tp = Ac; Ac = An; An = tp;
        tp = Bc; Bc = Bn; Bn = tp;
    }

    const int cr = (lane >> 4) * 4;
    const int cc = lane & 15;
    #pragma unroll
    for (int m = 0; m < 4; m++) {
        #pragma unroll
        for (int n = 0; n < 4; n++) {
            #pragma unroll
            for (int r = 0; r < 4; r++) {
                int grow = m0 + wr * 64 + m * 16 + cr + r;
                int gcol = n0 + wc * 64 + n * 16 + cc;
                size_t idx = (size_t)grow * N + gcol;
                float val = acc[m][n][r];
                if (EPI == 1) {
                    if (gcol < 1024) val = fmaxf(val, 0.f) + 1e-3f;
                    Cf[idx] = val;
                } else if (EPI == 2) {
                    Cf[idx] += val;
                } else if (EPI == 3) {
                    val += bias[gcol];
                    Cb[idx] = (__bf16)gelu_tanh(val);
                } else if (EPI == 4) {
                    Cf[idx] += val + bias[gcol];
                } else {
                    Cf[idx] = val;
                }
            }
        }
    }
}

// ---------------- kv partial: per (b,h,chunk) 64x64 + pksum column ----------------
__global__ __launch_bounds__(256) void kv_partial(const float* __restrict__ qkv,
                                                  float* __restrict__ part) {
    int bh = blockIdx.x;           // 32
    int chunk = blockIdx.y;        // 16 chunks of 256 rows
    int b = bh >> 3, hh = bh & 7;
    int t = threadIdx.x;
    int f = t & 63, eg = t >> 6;   // e-base = eg*16
    size_t base = ((size_t)b * SEQ + (size_t)chunk * 256) * 1536;
    const float* kcol = qkv + base + 512 + hh * 64 + f;
    const float* vrow = qkv + base + 1024 + hh * 64 + eg * 16;
    float psum = 0.f;
    f32x4 a0 = {0.f,0.f,0.f,0.f}, a1 = a0, a2 = a0, a3 = a0;
    for (int s = 0; s < 256; s++) {
        size_t o = (size_t)s * 1536;
        float pk = kcol[o];
        psum += pk;
        f32x4 v0 = *(const f32x4*)(vrow + o);
        f32x4 v1 = *(const f32x4*)(vrow + o + 4);
        f32x4 v2 = *(const f32x4*)(vrow + o + 8);
        f32x4 v3 = *(const f32x4*)(vrow + o + 12);
        a0 += v0 * pk; a1 += v1 * pk; a2 += v2 * pk; a3 += v3 * pk;
    }
    float* dst = part + ((size_t)chunk * 32 + bh) * 4160 + (size_t)f * 65 + eg * 16;
    #pragma unroll
    for (int j = 0; j < 4; j++) { dst[j] = a0[j]; dst[4+j] = a1[j]; dst[8+j] = a2[j]; dst[12+j] = a3[j]; }
    if (eg == 0) dst[64] = psum;   // dst = ...+f*65, so dst[64] is the pksum slot
}

__global__ void kv_reduce(const float* __restrict__ part, float* __restrict__ kvfin) {
    int i = blockIdx.x * 256 + threadIdx.x;
    if (i >= 32 * 4160) return;
    float s = 0.f;
    #pragma unroll
    for (int c = 0; c < 16; c++) s += part[(size_t)c * (32 * 4160) + i];
    kvfin[i] = s;
}

// ---------------- num / den / divide -> attn (bf16) ----------------
__global__ __launch_bounds__(256) void num_attn(const float* __restrict__ qkv,
                                                const float* __restrict__ kvfin,
                                                __bf16* __restrict__ attn) {
    __shared__ float kvs[64][68];
    __shared__ float ps[64];
    int bh = blockIdx.x, chunk = blockIdx.y;   // 32 x 32
    int b = bh >> 3, hh = bh & 7;
    const float* src = kvfin + (size_t)bh * 4160;
    for (int i = threadIdx.x; i < 4160; i += 256) {
        int f = i / 65, e = i - f * 65;
        if (e < 64) kvs[f][e] = src[i]; else ps[f] = src[i];
    }
    __syncthreads();
    int t = threadIdx.x;
    int r = t >> 1, e0 = (t & 1) * 32;
    size_t row = (size_t)b * SEQ + (size_t)chunk * 128 + r;
    const float* pqr = qkv + row * 1536 + hh * 64;
    float pq[64];
    #pragma unroll
    for (int j = 0; j < 16; j++) {
        f32x4 v = *(const f32x4*)(pqr + 4 * j);
        pq[4*j] = v[0]; pq[4*j+1] = v[1]; pq[4*j+2] = v[2]; pq[4*j+3] = v[3];
    }
    float den = 0.f;
    #pragma unroll
    for (int f = 0; f < 64; f++) den += pq[f] * ps[f];
    f32x4 acc[8];
    #pragma unroll
    for (int j = 0; j < 8; j++) acc[j] = (f32x4){0.f,0.f,0.f,0.f};
    for (int f = 0; f < 64; f++) {
        float p = pq[f];
        #pragma unroll
        for (int j = 0; j < 8; j++) acc[j] += *(const f32x4*)(&kvs[f][e0 + 4 * j]) * p;
    }
    float rd = 1.f / den;
    __bf16* op = attn + row * 512 + hh * 64 + e0;
    #pragma unroll
    for (int j2 = 0; j2 < 4; j2++) {
        bf16x8 ov;
        #pragma unroll
        for (int k = 0; k < 8; k++) ov[k] = (__bf16)(acc[j2 * 2 + k / 4][k % 4] * rd);
        *(bf16x8*)(op + j2 * 8) = ov;
    }
}

extern "C" void kernel_launch(void* const* d_in, const int* in_sizes, int n_in,
                              void* d_out, int out_size, void* d_ws, size_t ws_size,
                              hipStream_t stream) {
    const int*   tokens = (const int*)d_in[0];
    const float* embed  = (const float*)d_in[1];
    const float* Wq     = (const float*)d_in[2];
    const float* Wk     = (const float*)d_in[3];
    const float* Wv     = (const float*)d_in[4];
    const float* Wo     = (const float*)d_in[5];
    const float* ln1_s  = (const float*)d_in[6];
    const float* ln1_b  = (const float*)d_in[7];
    const float* W1     = (const float*)d_in[8];
    const float* b1     = (const float*)d_in[9];
    const float* W2     = (const float*)d_in[10];
    const float* b2     = (const float*)d_in[11];
    const float* ln2_s  = (const float*)d_in[12];
    const float* ln2_b  = (const float*)d_in[13];
    const float* lnf_s  = (const float*)d_in[14];
    const float* lnf_b  = (const float*)d_in[15];
    float* out = (float*)d_out;

    float* ws = (float*)d_ws;
    size_t off = 0;
    float* pos = ws;               off += 2097152;            // 4096*512
    float* x   = ws + off;         off += 8388608;            // 16384*512
    __bf16* h    = (__bf16*)(ws + off); off += 4194304;       // 16384*512 bf16
    __bf16* attn = (__bf16*)(ws + off); off += 4194304;       // 16384*512 bf16
    float* qkv = ws + off;         off += 25165824;           // 16384*1536 fp32 (reused as hid bf16)
    __bf16* hid = (__bf16*)qkv;
    float* kvpart = ws + off;      off += 16 * 32 * 4160;     // partials
    float* kvfin  = ws + off;      off += 32 * 4160;
    __bf16* wbuf  = (__bf16*)(ws + off);                      // 6 * 3145728 bf16

    pos_kernel<<<4096, 256, 0, stream>>>(pos);
    // batched weight transposes: one launch per weight tensor, z = layer
    transpose_bf16<<<dim3(16, 16, 6), dim3(32, 8), 0, stream>>>(Wq, wbuf,          512, 512,  262144, 3145728);
    transpose_bf16<<<dim3(16, 16, 6), dim3(32, 8), 0, stream>>>(Wk, wbuf + 262144, 512, 512,  262144, 3145728);
    transpose_bf16<<<dim3(16, 16, 6), dim3(32, 8), 0, stream>>>(Wv, wbuf + 524288, 512, 512,  262144, 3145728);
    transpose_bf16<<<dim3(16, 16, 6), dim3(32, 8), 0, stream>>>(Wo, wbuf + 786432, 512, 512,  262144, 3145728);
    transpose_bf16<<<dim3(64, 16, 6), dim3(32, 8), 0, stream>>>(W1, wbuf + 1048576, 512, 2048, 1048576, 3145728);
    transpose_bf16<<<dim3(16, 64, 6), dim3(32, 8), 0, stream>>>(W2, wbuf + 2097152, 2048, 512, 1048576, 3145728);
    embed_kernel<<<16384, 128, 0, stream>>>(tokens, embed, pos, x);

    for (int l = 0; l < 6; l++) {
        const __bf16* wl = wbuf + (size_t)l * 3145728;
        ln_kernel<1><<<4096, 256, 0, stream>>>(x, ln1_s + l * 512, ln1_b + l * 512, h, nullptr);
        gemm_bt<1, 512><<<dim3(128, 12), 256, 0, stream>>>(h, wl, qkv, nullptr, nullptr, 1536);
        kv_partial<<<dim3(32, 16), 256, 0, stream>>>(qkv, kvpart);
        kv_reduce<<<520, 256, 0, stream>>>(kvpart, kvfin);
        num_attn<<<dim3(32, 32), 256, 0, stream>>>(qkv, kvfin, attn);
        gemm_bt<2, 512><<<dim3(128, 4), 256, 0, stream>>>(attn, wl + 786432, x, nullptr, nullptr, 512);
        ln_kernel<1><<<4096, 256, 0, stream>>>(x, ln2_s + l * 512, ln2_b + l * 512, h, nullptr);
        gemm_bt<3, 512><<<dim3(128, 16), 256, 0, stream>>>(h, wl + 1048576, nullptr, hid, b1 + (size_t)l * 2048, 2048);
        gemm_bt<4, 2048><<<dim3(128, 4), 256, 0, stream>>>(hid, wl + 2097152, x, nullptr, b2 + (size_t)l * 512, 512);
    }
    ln_kernel<0><<<4096, 256, 0, stream>>>(x, lnf_s, lnf_b, nullptr, out);
}

// Round 4
// 1878.052 us; speedup vs baseline: 1.1132x; 1.1132x over previous
//
#include <hip/hip_runtime.h>

typedef float f32x4 __attribute__((ext_vector_type(4)));
typedef __bf16 bf16x8 __attribute__((ext_vector_type(8)));

#define NROWS 16384   // B*S
#define SEQ   4096
#define EMBD  512
#define MLPD  2048

__device__ inline float gelu_tanh(float x) {
    float t = 0.7978845608028654f * (x + 0.044715f * x * x * x);
    float e = __expf(2.f * t);
    float th = 1.f - 2.f / (1.f + e);
    return 0.5f * x * (1.f + th);
}

// direct global->LDS 16B DMA; LDS dest must be linear in lane order
#define GLOAD16(gp, lp)                                                        \
    __builtin_amdgcn_global_load_lds(                                          \
        (const __attribute__((address_space(1))) void*)(gp),                   \
        (__attribute__((address_space(3))) void*)(lp), 16, 0, 0)

// ---------------- positional table: pos[s][512] ----------------
__global__ void pos_kernel(float* __restrict__ pos) {
    int i = blockIdx.x * 256 + threadIdx.x;        // 4096*256
    int s = i >> 8, j = i & 255;
    float div = __expf((float)j * (-2.f * 9.210340371976184f / 512.f));
    float a = (float)s * div;
    pos[(size_t)s * 512 + 2 * j]     = sinf(a);
    pos[(size_t)s * 512 + 2 * j + 1] = cosf(a);
}

// ---------------- embedding gather + pos add ----------------
__global__ void embed_kernel(const int* __restrict__ tokens,
                             const float* __restrict__ embed,
                             const float* __restrict__ pos,
                             float* __restrict__ x) {
    int row = blockIdx.x;            // 16384
    int t = threadIdx.x;             // 128
    int s = row & (SEQ - 1);
    int tok = tokens[row];
    f32x4 e = *(const f32x4*)(embed + (size_t)tok * 512 + t * 4);
    f32x4 p = *(const f32x4*)(pos + (size_t)s * 512 + t * 4);
    e += p;
    *(f32x4*)(x + (size_t)row * 512 + t * 4) = e;
}

// ---------------- transpose fp32 [K][N] -> bf16 [N][K], batched over z ----------------
__global__ void transpose_bf16(const float* __restrict__ in, __bf16* __restrict__ out,
                               int K, int N, size_t in_lstride, size_t out_lstride) {
    __shared__ float tile[32][33];
    in  += (size_t)blockIdx.z * in_lstride;
    out += (size_t)blockIdx.z * out_lstride;
    int n0 = blockIdx.x * 32, k0 = blockIdx.y * 32;
    int tx = threadIdx.x, ty = threadIdx.y;   // 32 x 8
    #pragma unroll
    for (int i = 0; i < 32; i += 8)
        tile[ty + i][tx] = in[(size_t)(k0 + ty + i) * N + n0 + tx];
    __syncthreads();
    #pragma unroll
    for (int i = 0; i < 32; i += 8)
        out[(size_t)(n0 + ty + i) * K + k0 + tx] = (__bf16)tile[tx][ty + i];
}

// ---------------- LayerNorm (one wave per 512-row) ----------------
template<int OUTBF>
__global__ __launch_bounds__(256) void ln_kernel(
    const float* __restrict__ x, const float* __restrict__ gamma,
    const float* __restrict__ beta, __bf16* __restrict__ outb,
    float* __restrict__ outf) {
    int lane = threadIdx.x & 63;
    size_t row = (size_t)blockIdx.x * 4 + (threadIdx.x >> 6);
    const float* xr = x + row * 512 + lane * 8;
    f32x4 v0 = *(const f32x4*)xr;
    f32x4 v1 = *(const f32x4*)(xr + 4);
    float sum = (v0[0] + v0[1]) + (v0[2] + v0[3]) + (v1[0] + v1[1]) + (v1[2] + v1[3]);
    #pragma unroll
    for (int off = 32; off; off >>= 1) sum += __shfl_xor(sum, off);
    float mu = sum * (1.f / 512.f);
    float vs = 0.f;
    #pragma unroll
    for (int j = 0; j < 4; j++) {
        float d0 = v0[j] - mu; vs += d0 * d0;
        float d1 = v1[j] - mu; vs += d1 * d1;
    }
    #pragma unroll
    for (int off = 32; off; off >>= 1) vs += __shfl_xor(vs, off);
    float inv = rsqrtf(vs * (1.f / 512.f) + 1e-6f);
    const float* gp = gamma + lane * 8;
    const float* bp = beta + lane * 8;
    f32x4 g0 = *(const f32x4*)gp, g1 = *(const f32x4*)(gp + 4);
    f32x4 bb0 = *(const f32x4*)bp, bb1 = *(const f32x4*)(bp + 4);
    float o[8];
    #pragma unroll
    for (int j = 0; j < 4; j++) {
        o[j]     = (v0[j] - mu) * inv * g0[j] + bb0[j];
        o[4 + j] = (v1[j] - mu) * inv * g1[j] + bb1[j];
    }
    if (OUTBF) {
        bf16x8 ov;
        #pragma unroll
        for (int j = 0; j < 8; j++) ov[j] = (__bf16)o[j];
        *(bf16x8*)(outb + row * 512 + lane * 8) = ov;
    } else {
        f32x4 o0 = {o[0], o[1], o[2], o[3]};
        f32x4 o1 = {o[4], o[5], o[6], o[7]};
        *(f32x4*)(outf + row * 512 + lane * 8) = o0;
        *(f32x4*)(outf + row * 512 + lane * 8 + 4) = o1;
    }
}

// ---------------- MFMA GEMM: C[M,N] = A[M,K](bf16) @ BT[N,K](bf16) ----------------
// 128x128 tile, BK=64, double-buffered LDS, fine 2-phase interleave per K-tile:
//   ph0: issue 4 gload_lds(next) -> vmcnt(4) -> barrier -> ds_read kk0 -> 16 MFMA -> barrier
//   ph1: issue 4 gload_lds(next) ->            barrier -> ds_read kk1 -> 16 MFMA -> barrier
// vmcnt(4) = counted (next tile's 4 stay in flight across 2 compute phases).
// Every vmcnt precedes a barrier that precedes any ds_read of that buffer.
// LDS: 8x16B chunks/row, chunk XOR (row&7); linear dest + pre-swizzled source.
// 1-D grid, bijective XCD-chunk swizzle (m204), nb-fastest for A-panel L2 reuse.
// EPI: 1 = qkv (phi on cols<1024, fp32 out ld=N)
//      2 = residual add into Cf
//      3 = +bias, gelu, bf16 out
//      4 = +bias, residual add into Cf
template<int EPI, int K>
__global__ __launch_bounds__(256, 2) void gemm_bt(
    const __bf16* __restrict__ A, const __bf16* __restrict__ BT,
    float* __restrict__ Cf, __bf16* __restrict__ Cb,
    const float* __restrict__ bias, int N, int nbn) {
    constexpr int NT = K / 64;
    __shared__ __align__(16) __bf16 Abuf[2][128 * 64];
    __shared__ __align__(16) __bf16 Bbuf[2][128 * 64];
    const int t = threadIdx.x;
    const int lane = t & 63;
    const int wave = t >> 6;
    const int wr = wave >> 1, wc = wave & 1;
    // bijective XCD swizzle: consecutive swz share mb (A-panel) within an XCD chunk
    const int nblk = gridDim.x;
    const int q = nblk >> 3, r = nblk & 7;
    const int xcd = blockIdx.x & 7, loc = blockIdx.x >> 3;
    const int swz = (xcd < r ? xcd * (q + 1) : r * (q + 1) + (xcd - r) * q) + loc;
    const int m0 = (swz / nbn) * 128, n0 = (swz % nbn) * 128;
    const int fr = lane & 15, fc = lane >> 4;

    // staging: thread t owns 16B-slots {t, t+256, t+512, t+768}
    const __bf16* Aps[4];
    const __bf16* Bps[4];
    int lslot[4];
    #pragma unroll
    for (int j = 0; j < 4; j++) {
        int slot = t + 256 * j;
        int row = slot >> 3, cp = slot & 7;
        int sc = cp ^ (row & 7);               // pre-swizzled source chunk
        Aps[j] = A  + (size_t)(m0 + row) * K + sc * 8;
        Bps[j] = BT + (size_t)(n0 + row) * K + sc * 8;
        lslot[j] = slot * 8;
    }

    f32x4 acc[4][4];
    #pragma unroll
    for (int m = 0; m < 4; m++)
        #pragma unroll
        for (int n = 0; n < 4; n++)
            acc[m][n] = (f32x4){0.f, 0.f, 0.f, 0.f};

    auto stage_half = [&](int j0, __bf16* Ad, __bf16* Bd, int koff) {
        #pragma unroll
        for (int j = 0; j < 2; j++) {
            GLOAD16(Aps[j0 + j] + koff, Ad + lslot[j0 + j]);
            GLOAD16(Bps[j0 + j] + koff, Bd + lslot[j0 + j]);
        }
    };
    auto compute_half = [&](const __bf16* Ac, const __bf16* Bc, int kk) {
        bf16x8 af[4], bfr[4];
        #pragma unroll
        for (int m = 0; m < 4; m++) {
            int ra = wr * 64 + m * 16 + fr;
            int rb = wc * 64 + m * 16 + fr;
            int c = kk * 4 + fc;
            af[m]  = *(const bf16x8*)(Ac + ra * 64 + ((c ^ (ra & 7)) << 3));
            bfr[m] = *(const bf16x8*)(Bc + rb * 64 + ((c ^ (rb & 7)) << 3));
        }
        __builtin_amdgcn_s_setprio(1);
        #pragma unroll
        for (int m = 0; m < 4; m++)
            #pragma unroll
            for (int n = 0; n < 4; n++)
                acc[m][n] = __builtin_amdgcn_mfma_f32_16x16x32_bf16(af[m], bfr[n], acc[m][n], 0, 0, 0);
        __builtin_amdgcn_s_setprio(0);
    };

    int cur = 0;
    stage_half(0, Abuf[0], Bbuf[0], 0);
    stage_half(2, Abuf[0], Bbuf[0], 0);

    for (int s = 0; s < NT; s++) {
        __bf16* Ac = Abuf[cur];     __bf16* Bc = Bbuf[cur];
        __bf16* An = Abuf[cur ^ 1]; __bf16* Bn = Bbuf[cur ^ 1];
        const int koff = (s + 1) * 64;
        // ---- phase 0 ----
        if (s + 1 < NT) {
            stage_half(0, An, Bn, koff);
            asm volatile("s_waitcnt vmcnt(4)" ::: "memory");  // cur tile landed, 4 in flight
        } else {
            asm volatile("s_waitcnt vmcnt(0)" ::: "memory");
        }
        __builtin_amdgcn_s_barrier();
        compute_half(Ac, Bc, 0);
        __builtin_amdgcn_s_barrier();
        // ---- phase 1 ----
        if (s + 1 < NT) stage_half(2, An, Bn, koff);
        __builtin_amdgcn_s_barrier();
        compute_half(Ac, Bc, 1);
        __builtin_amdgcn_s_barrier();
        cur ^= 1;
    }

    const int cr = (lane >> 4) * 4;
    const int cc = lane & 15;
    #pragma unroll
    for (int m = 0; m < 4; m++) {
        #pragma unroll
        for (int n = 0; n < 4; n++) {
            #pragma unroll
            for (int r2 = 0; r2 < 4; r2++) {
                int grow = m0 + wr * 64 + m * 16 + cr + r2;
                int gcol = n0 + wc * 64 + n * 16 + cc;
                size_t idx = (size_t)grow * N + gcol;
                float val = acc[m][n][r2];
                if (EPI == 1) {
                    if (gcol < 1024) val = fmaxf(val, 0.f) + 1e-3f;
                    Cf[idx] = val;
                } else if (EPI == 2) {
                    Cf[idx] += val;
                } else if (EPI == 3) {
                    val += bias[gcol];
                    Cb[idx] = (__bf16)gelu_tanh(val);
                } else if (EPI == 4) {
                    Cf[idx] += val + bias[gcol];
                } else {
                    Cf[idx] = val;
                }
            }
        }
    }
}

// ---------------- kv partial: per (b,h,chunk) 64x64 + pksum column ----------------
__global__ __launch_bounds__(256) void kv_partial(const float* __restrict__ qkv,
                                                  float* __restrict__ part) {
    int bh = blockIdx.x;           // 32
    int chunk = blockIdx.y;        // 16 chunks of 256 rows
    int b = bh >> 3, hh = bh & 7;
    int t = threadIdx.x;
    int f = t & 63, eg = t >> 6;   // e-base = eg*16
    size_t base = ((size_t)b * SEQ + (size_t)chunk * 256) * 1536;
    const float* kcol = qkv + base + 512 + hh * 64 + f;
    const float* vrow = qkv + base + 1024 + hh * 64 + eg * 16;
    float psum = 0.f;
    f32x4 a0 = {0.f,0.f,0.f,0.f}, a1 = a0, a2 = a0, a3 = a0;
    for (int s = 0; s < 256; s++) {
        size_t o = (size_t)s * 1536;
        float pk = kcol[o];
        psum += pk;
        f32x4 v0 = *(const f32x4*)(vrow + o);
        f32x4 v1 = *(const f32x4*)(vrow + o + 4);
        f32x4 v2 = *(const f32x4*)(vrow + o + 8);
        f32x4 v3 = *(const f32x4*)(vrow + o + 12);
        a0 += v0 * pk; a1 += v1 * pk; a2 += v2 * pk; a3 += v3 * pk;
    }
    float* dst = part + ((size_t)chunk * 32 + bh) * 4160 + (size_t)f * 65 + eg * 16;
    #pragma unroll
    for (int j = 0; j < 4; j++) { dst[j] = a0[j]; dst[4+j] = a1[j]; dst[8+j] = a2[j]; dst[12+j] = a3[j]; }
    if (eg == 0) dst[64] = psum;   // dst = ...+f*65, so dst[64] is the pksum slot
}

__global__ void kv_reduce(const float* __restrict__ part, float* __restrict__ kvfin) {
    int i = blockIdx.x * 256 + threadIdx.x;
    if (i >= 32 * 4160) return;
    float s = 0.f;
    #pragma unroll
    for (int c = 0; c < 16; c++) s += part[(size_t)c * (32 * 4160) + i];
    kvfin[i] = s;
}

// ---------------- num / den / divide -> attn (bf16) ----------------
__global__ __launch_bounds__(256) void num_attn(const float* __restrict__ qkv,
                                                const float* __restrict__ kvfin,
                                                __bf16* __restrict__ attn) {
    __shared__ float kvs[64][68];
    __shared__ float ps[64];
    int bh = blockIdx.x, chunk = blockIdx.y;   // 32 x 32
    int b = bh >> 3, hh = bh & 7;
    const float* src = kvfin + (size_t)bh * 4160;
    for (int i = threadIdx.x; i < 4160; i += 256) {
        int f = i / 65, e = i - f * 65;
        if (e < 64) kvs[f][e] = src[i]; else ps[f] = src[i];
    }
    __syncthreads();
    int t = threadIdx.x;
    int r = t >> 1, e0 = (t & 1) * 32;
    size_t row = (size_t)b * SEQ + (size_t)chunk * 128 + r;
    const float* pqr = qkv + row * 1536 + hh * 64;
    float pq[64];
    #pragma unroll
    for (int j = 0; j < 16; j++) {
        f32x4 v = *(const f32x4*)(pqr + 4 * j);
        pq[4*j] = v[0]; pq[4*j+1] = v[1]; pq[4*j+2] = v[2]; pq[4*j+3] = v[3];
    }
    float den = 0.f;
    #pragma unroll
    for (int f = 0; f < 64; f++) den += pq[f] * ps[f];
    f32x4 acc[8];
    #pragma unroll
    for (int j = 0; j < 8; j++) acc[j] = (f32x4){0.f,0.f,0.f,0.f};
    for (int f = 0; f < 64; f++) {
        float p = pq[f];
        #pragma unroll
        for (int j = 0; j < 8; j++) acc[j] += *(const f32x4*)(&kvs[f][e0 + 4 * j]) * p;
    }
    float rd = 1.f / den;
    __bf16* op = attn + row * 512 + hh * 64 + e0;
    #pragma unroll
    for (int j2 = 0; j2 < 4; j2++) {
        bf16x8 ov;
        #pragma unroll
        for (int k = 0; k < 8; k++) ov[k] = (__bf16)(acc[j2 * 2 + k / 4][k % 4] * rd);
        *(bf16x8*)(op + j2 * 8) = ov;
    }
}

extern "C" void kernel_launch(void* const* d_in, const int* in_sizes, int n_in,
                              void* d_out, int out_size, void* d_ws, size_t ws_size,
                              hipStream_t stream) {
    const int*   tokens = (const int*)d_in[0];
    const float* embed  = (const float*)d_in[1];
    const float* Wq     = (const float*)d_in[2];
    const float* Wk     = (const float*)d_in[3];
    const float* Wv     = (const float*)d_in[4];
    const float* Wo     = (const float*)d_in[5];
    const float* ln1_s  = (const float*)d_in[6];
    const float* ln1_b  = (const float*)d_in[7];
    const float* W1     = (const float*)d_in[8];
    const float* b1     = (const float*)d_in[9];
    const float* W2     = (const float*)d_in[10];
    const float* b2     = (const float*)d_in[11];
    const float* ln2_s  = (const float*)d_in[12];
    const float* ln2_b  = (const float*)d_in[13];
    const float* lnf_s  = (const float*)d_in[14];
    const float* lnf_b  = (const float*)d_in[15];
    float* out = (float*)d_out;

    float* ws = (float*)d_ws;
    size_t off = 0;
    float* pos = ws;               off += 2097152;            // 4096*512
    float* x   = ws + off;         off += 8388608;            // 16384*512
    __bf16* h    = (__bf16*)(ws + off); off += 4194304;       // 16384*512 bf16
    __bf16* attn = (__bf16*)(ws + off); off += 4194304;       // 16384*512 bf16
    float* qkv = ws + off;         off += 25165824;           // 16384*1536 fp32 (reused as hid bf16)
    __bf16* hid = (__bf16*)qkv;
    float* kvpart = ws + off;      off += 16 * 32 * 4160;     // partials
    float* kvfin  = ws + off;      off += 32 * 4160;
    __bf16* wbuf  = (__bf16*)(ws + off);                      // 6 * 3145728 bf16

    pos_kernel<<<4096, 256, 0, stream>>>(pos);
    // batched weight transposes: one launch per weight tensor, z = layer
    transpose_bf16<<<dim3(16, 16, 6), dim3(32, 8), 0, stream>>>(Wq, wbuf,          512, 512,  262144, 3145728);
    transpose_bf16<<<dim3(16, 16, 6), dim3(32, 8), 0, stream>>>(Wk, wbuf + 262144, 512, 512,  262144, 3145728);
    transpose_bf16<<<dim3(16, 16, 6), dim3(32, 8), 0, stream>>>(Wv, wbuf + 524288, 512, 512,  262144, 3145728);
    transpose_bf16<<<dim3(16, 16, 6), dim3(32, 8), 0, stream>>>(Wo, wbuf + 786432, 512, 512,  262144, 3145728);
    transpose_bf16<<<dim3(64, 16, 6), dim3(32, 8), 0, stream>>>(W1, wbuf + 1048576, 512, 2048, 1048576, 3145728);
    transpose_bf16<<<dim3(16, 64, 6), dim3(32, 8), 0, stream>>>(W2, wbuf + 2097152, 2048, 512, 1048576, 3145728);
    embed_kernel<<<16384, 128, 0, stream>>>(tokens, embed, pos, x);

    for (int l = 0; l < 6; l++) {
        const __bf16* wl = wbuf + (size_t)l * 3145728;
        ln_kernel<1><<<4096, 256, 0, stream>>>(x, ln1_s + l * 512, ln1_b + l * 512, h, nullptr);
        gemm_bt<1, 512><<<1536, 256, 0, stream>>>(h, wl, qkv, nullptr, nullptr, 1536, 12);
        kv_partial<<<dim3(32, 16), 256, 0, stream>>>(qkv, kvpart);
        kv_reduce<<<520, 256, 0, stream>>>(kvpart, kvfin);
        num_attn<<<dim3(32, 32), 256, 0, stream>>>(qkv, kvfin, attn);
        gemm_bt<2, 512><<<512, 256, 0, stream>>>(attn, wl + 786432, x, nullptr, nullptr, 512, 4);
        ln_kernel<1><<<4096, 256, 0, stream>>>(x, ln2_s + l * 512, ln2_b + l * 512, h, nullptr);
        gemm_bt<3, 512><<<2048, 256, 0, stream>>>(h, wl + 1048576, nullptr, hid, b1 + (size_t)l * 2048, 2048, 16);
        gemm_bt<4, 2048><<<512, 256, 0, stream>>>(hid, wl + 2097152, x, nullptr, b2 + (size_t)l * 512, 512, 4);
    }
    ln_kernel<0><<<4096, 256, 0, stream>>>(x, lnf_s, lnf_b, nullptr, out);
}

// Round 5
// 1763.386 us; speedup vs baseline: 1.1856x; 1.0650x over previous
//
#include <hip/hip_runtime.h>

typedef float f32x4 __attribute__((ext_vector_type(4)));
typedef __bf16 bf16x8 __attribute__((ext_vector_type(8)));

#define NROWS 16384   // B*S
#define SEQ   4096
#define EMBD  512
#define MLPD  2048

__device__ inline float gelu_tanh(float x) {
    float t = 0.7978845608028654f * (x + 0.044715f * x * x * x);
    float e = __expf(2.f * t);
    float th = 1.f - 2.f / (1.f + e);
    return 0.5f * x * (1.f + th);
}

// direct global->LDS 16B DMA; LDS dest must be linear in lane order
#define GLOAD16(gp, lp)                                                        \
    __builtin_amdgcn_global_load_lds(                                          \
        (const __attribute__((address_space(1))) void*)(gp),                   \
        (__attribute__((address_space(3))) void*)(lp), 16, 0, 0)

// ---------------- positional table: pos[s][512] ----------------
__global__ void pos_kernel(float* __restrict__ pos) {
    int i = blockIdx.x * 256 + threadIdx.x;        // 4096*256
    int s = i >> 8, j = i & 255;
    float div = __expf((float)j * (-2.f * 9.210340371976184f / 512.f));
    float a = (float)s * div;
    pos[(size_t)s * 512 + 2 * j]     = sinf(a);
    pos[(size_t)s * 512 + 2 * j + 1] = cosf(a);
}

// ---------------- embedding gather + pos add ----------------
__global__ void embed_kernel(const int* __restrict__ tokens,
                             const float* __restrict__ embed,
                             const float* __restrict__ pos,
                             float* __restrict__ x) {
    int row = blockIdx.x;            // 16384
    int t = threadIdx.x;             // 128
    int s = row & (SEQ - 1);
    int tok = tokens[row];
    f32x4 e = *(const f32x4*)(embed + (size_t)tok * 512 + t * 4);
    f32x4 p = *(const f32x4*)(pos + (size_t)s * 512 + t * 4);
    e += p;
    *(f32x4*)(x + (size_t)row * 512 + t * 4) = e;
}

// ---------------- transpose fp32 [K][N] -> bf16 [N][K], batched over z ----------------
__global__ void transpose_bf16(const float* __restrict__ in, __bf16* __restrict__ out,
                               int K, int N, size_t in_lstride, size_t out_lstride) {
    __shared__ float tile[32][33];
    in  += (size_t)blockIdx.z * in_lstride;
    out += (size_t)blockIdx.z * out_lstride;
    int n0 = blockIdx.x * 32, k0 = blockIdx.y * 32;
    int tx = threadIdx.x, ty = threadIdx.y;   // 32 x 8
    #pragma unroll
    for (int i = 0; i < 32; i += 8)
        tile[ty + i][tx] = in[(size_t)(k0 + ty + i) * N + n0 + tx];
    __syncthreads();
    #pragma unroll
    for (int i = 0; i < 32; i += 8)
        out[(size_t)(n0 + ty + i) * K + k0 + tx] = (__bf16)tile[tx][ty + i];
}

// ---------------- LayerNorm (one wave per 512-row) ----------------
template<int OUTBF>
__global__ __launch_bounds__(256) void ln_kernel(
    const float* __restrict__ x, const float* __restrict__ gamma,
    const float* __restrict__ beta, __bf16* __restrict__ outb,
    float* __restrict__ outf) {
    int lane = threadIdx.x & 63;
    size_t row = (size_t)blockIdx.x * 4 + (threadIdx.x >> 6);
    const float* xr = x + row * 512 + lane * 8;
    f32x4 v0 = *(const f32x4*)xr;
    f32x4 v1 = *(const f32x4*)(xr + 4);
    float sum = (v0[0] + v0[1]) + (v0[2] + v0[3]) + (v1[0] + v1[1]) + (v1[2] + v1[3]);
    #pragma unroll
    for (int off = 32; off; off >>= 1) sum += __shfl_xor(sum, off);
    float mu = sum * (1.f / 512.f);
    float vs = 0.f;
    #pragma unroll
    for (int j = 0; j < 4; j++) {
        float d0 = v0[j] - mu; vs += d0 * d0;
        float d1 = v1[j] - mu; vs += d1 * d1;
    }
    #pragma unroll
    for (int off = 32; off; off >>= 1) vs += __shfl_xor(vs, off);
    float inv = rsqrtf(vs * (1.f / 512.f) + 1e-6f);
    const float* gp = gamma + lane * 8;
    const float* bp = beta + lane * 8;
    f32x4 g0 = *(const f32x4*)gp, g1 = *(const f32x4*)(gp + 4);
    f32x4 bb0 = *(const f32x4*)bp, bb1 = *(const f32x4*)(bp + 4);
    float o[8];
    #pragma unroll
    for (int j = 0; j < 4; j++) {
        o[j]     = (v0[j] - mu) * inv * g0[j] + bb0[j];
        o[4 + j] = (v1[j] - mu) * inv * g1[j] + bb1[j];
    }
    if (OUTBF) {
        bf16x8 ov;
        #pragma unroll
        for (int j = 0; j < 8; j++) ov[j] = (__bf16)o[j];
        *(bf16x8*)(outb + row * 512 + lane * 8) = ov;
    } else {
        f32x4 o0 = {o[0], o[1], o[2], o[3]};
        f32x4 o1 = {o[4], o[5], o[6], o[7]};
        *(f32x4*)(outf + row * 512 + lane * 8) = o0;
        *(f32x4*)(outf + row * 512 + lane * 8 + 4) = o1;
    }
}

// ---------------- MFMA GEMM: C[M,N] = A[M,K](bf16) @ BT[N,K](bf16) ----------------
// 128x128 tile, BK=32, double-buffered LDS (32 KB total -> 4-5 blocks/CU),
// counted vmcnt(4): next K-tile's 4 global_load_lds stay in flight across the
// barrier while current tile computes (T4). LDS swizzle for 64B rows:
// chunk ^= (row>>1)&3 (8 bank-groups covered per 8 rows -> 2-way = free).
// Linear LDS dest + pre-swizzled global source (rule #21).
// 1-D grid, bijective XCD-chunk swizzle (m204), nb-fastest for A-panel L2 reuse.
// EPI: 1 = qkv -> bf16 out, phi on cols<1024
//      2 = residual add into Cf
//      3 = +bias, gelu, bf16 out
//      4 = +bias, residual add into Cf
template<int EPI, int K>
__global__ __launch_bounds__(256, 4) void gemm_bt(
    const __bf16* __restrict__ A, const __bf16* __restrict__ BT,
    float* __restrict__ Cf, __bf16* __restrict__ Cb,
    const float* __restrict__ bias, int N, int nbn) {
    constexpr int NT = K / 32;
    __shared__ __align__(16) __bf16 Abuf[2][128 * 32];
    __shared__ __align__(16) __bf16 Bbuf[2][128 * 32];
    const int t = threadIdx.x;
    const int lane = t & 63;
    const int wave = t >> 6;
    const int wr = wave >> 1, wc = wave & 1;
    const int nblk = gridDim.x;
    const int q = nblk >> 3, r = nblk & 7;
    const int xcd = blockIdx.x & 7, loc = blockIdx.x >> 3;
    const int swz = (xcd < r ? xcd * (q + 1) : r * (q + 1) + (xcd - r) * q) + loc;
    const int m0 = (swz / nbn) * 128, n0 = (swz % nbn) * 128;
    const int fr = lane & 15, fc = lane >> 4;

    // staging: 128 rows x 4 chunks(16B) = 512 slots per matrix; thread t owns
    // slots {t, t+256} of A and of B.
    const __bf16* Aps[2];
    const __bf16* Bps[2];
    int lslot[2];
    #pragma unroll
    for (int j = 0; j < 2; j++) {
        int slot = t + 256 * j;
        int row = slot >> 2, cp = slot & 3;
        int sc = cp ^ ((row >> 1) & 3);        // pre-swizzled source chunk
        Aps[j] = A  + (size_t)(m0 + row) * K + sc * 8;
        Bps[j] = BT + (size_t)(n0 + row) * K + sc * 8;
        lslot[j] = slot * 8;
    }

    f32x4 acc[4][4];
    #pragma unroll
    for (int m = 0; m < 4; m++)
        #pragma unroll
        for (int n = 0; n < 4; n++)
            acc[m][n] = (f32x4){0.f, 0.f, 0.f, 0.f};

    auto stage = [&](int koff, __bf16* Ad, __bf16* Bd) {
        #pragma unroll
        for (int j = 0; j < 2; j++) {
            GLOAD16(Aps[j] + koff, Ad + lslot[j]);
            GLOAD16(Bps[j] + koff, Bd + lslot[j]);
        }
    };

    int cur = 0;
    stage(0, Abuf[0], Bbuf[0]);

    for (int s = 0; s < NT; s++) {
        __bf16* Ac = Abuf[cur];     __bf16* Bc = Bbuf[cur];
        if (s + 1 < NT) {
            stage((s + 1) * 32, Abuf[cur ^ 1], Bbuf[cur ^ 1]);
            asm volatile("s_waitcnt vmcnt(4)" ::: "memory");  // cur tile landed; next 4 in flight
        } else {
            asm volatile("s_waitcnt vmcnt(0)" ::: "memory");
        }
        __builtin_amdgcn_s_barrier();

        bf16x8 af[4], bfr[4];
        #pragma unroll
        for (int m = 0; m < 4; m++) {
            int ra = wr * 64 + m * 16 + fr;
            int rb = wc * 64 + m * 16 + fr;
            af[m]  = *(const bf16x8*)(Ac + ra * 32 + ((fc ^ ((ra >> 1) & 3)) << 3));
            bfr[m] = *(const bf16x8*)(Bc + rb * 32 + ((fc ^ ((rb >> 1) & 3)) << 3));
        }
        __builtin_amdgcn_s_setprio(1);
        #pragma unroll
        for (int m = 0; m < 4; m++)
            #pragma unroll
            for (int n = 0; n < 4; n++)
                acc[m][n] = __builtin_amdgcn_mfma_f32_16x16x32_bf16(af[m], bfr[n], acc[m][n], 0, 0, 0);
        __builtin_amdgcn_s_setprio(0);
        __builtin_amdgcn_s_barrier();   // readers done before overwrite of this buffer
        cur ^= 1;
    }

    const int cr = (lane >> 4) * 4;
    const int cc = lane & 15;
    #pragma unroll
    for (int m = 0; m < 4; m++) {
        #pragma unroll
        for (int n = 0; n < 4; n++) {
            #pragma unroll
            for (int r2 = 0; r2 < 4; r2++) {
                int grow = m0 + wr * 64 + m * 16 + cr + r2;
                int gcol = n0 + wc * 64 + n * 16 + cc;
                size_t idx = (size_t)grow * N + gcol;
                float val = acc[m][n][r2];
                if (EPI == 1) {
                    if (gcol < 1024) val = fmaxf(val, 0.f) + 1e-3f;
                    Cb[idx] = (__bf16)val;
                } else if (EPI == 2) {
                    Cf[idx] += val;
                } else if (EPI == 3) {
                    val += bias[gcol];
                    Cb[idx] = (__bf16)gelu_tanh(val);
                } else if (EPI == 4) {
                    Cf[idx] += val + bias[gcol];
                } else {
                    Cf[idx] = val;
                }
            }
        }
    }
}

// ---------------- kv partial: per (b,h,chunk of 64 rows) 64x64 + pksum ----------------
__global__ __launch_bounds__(256) void kv_partial(const __bf16* __restrict__ qkvb,
                                                  float* __restrict__ part) {
    int bh = blockIdx.x;           // 32
    int chunk = blockIdx.y;        // 64 chunks of 64 rows
    int b = bh >> 3, hh = bh & 7;
    int t = threadIdx.x;
    int f = t & 63, eg = t >> 6;   // e-base = eg*16
    size_t base = ((size_t)b * SEQ + (size_t)chunk * 64) * 1536;
    const __bf16* kcol = qkvb + base + 512 + hh * 64 + f;
    const __bf16* vrow = qkvb + base + 1024 + hh * 64 + eg * 16;
    float psum = 0.f;
    f32x4 a0 = {0.f,0.f,0.f,0.f}, a1 = a0, a2 = a0, a3 = a0;
    for (int s = 0; s < 64; s++) {
        size_t o = (size_t)s * 1536;
        float pk = (float)kcol[o];
        psum += pk;
        bf16x8 w0 = *(const bf16x8*)(vrow + o);
        bf16x8 w1 = *(const bf16x8*)(vrow + o + 8);
        #pragma unroll
        for (int j = 0; j < 4; j++) {
            a0[j] += (float)w0[j]     * pk;
            a1[j] += (float)w0[4 + j] * pk;
            a2[j] += (float)w1[j]     * pk;
            a3[j] += (float)w1[4 + j] * pk;
        }
    }
    float* dst = part + ((size_t)chunk * 32 + bh) * 4160 + (size_t)f * 65 + eg * 16;
    #pragma unroll
    for (int j = 0; j < 4; j++) { dst[j] = a0[j]; dst[4+j] = a1[j]; dst[8+j] = a2[j]; dst[12+j] = a3[j]; }
    if (eg == 0) dst[64] = psum;   // pksum slot
}

__global__ void kv_reduce(const float* __restrict__ part, float* __restrict__ kvfin) {
    int i = blockIdx.x * 256 + threadIdx.x;
    if (i >= 32 * 4160) return;
    float s = 0.f;
    #pragma unroll 8
    for (int c = 0; c < 64; c++) s += part[(size_t)c * (32 * 4160) + i];
    kvfin[i] = s;
}

// ---------------- num / den / divide -> attn (bf16) ----------------
__global__ __launch_bounds__(256) void num_attn(const __bf16* __restrict__ qkvb,
                                                const float* __restrict__ kvfin,
                                                __bf16* __restrict__ attn) {
    __shared__ float kvs[64][68];
    __shared__ float ps[64];
    int bh = blockIdx.x, chunk = blockIdx.y;   // 32 x 32
    int b = bh >> 3, hh = bh & 7;
    const float* src = kvfin + (size_t)bh * 4160;
    for (int i = threadIdx.x; i < 4160; i += 256) {
        int f = i / 65, e = i - f * 65;
        if (e < 64) kvs[f][e] = src[i]; else ps[f] = src[i];
    }
    __syncthreads();
    int t = threadIdx.x;
    int r = t >> 1, e0 = (t & 1) * 32;
    size_t row = (size_t)b * SEQ + (size_t)chunk * 128 + r;
    const __bf16* pqr = qkvb + row * 1536 + hh * 64;
    float pq[64];
    #pragma unroll
    for (int j = 0; j < 8; j++) {
        bf16x8 v = *(const bf16x8*)(pqr + 8 * j);
        #pragma unroll
        for (int k = 0; k < 8; k++) pq[8 * j + k] = (float)v[k];
    }
    float den = 0.f;
    #pragma unroll
    for (int f = 0; f < 64; f++) den += pq[f] * ps[f];
    f32x4 acc[8];
    #pragma unroll
    for (int j = 0; j < 8; j++) acc[j] = (f32x4){0.f,0.f,0.f,0.f};
    for (int f = 0; f < 64; f++) {
        float p = pq[f];
        #pragma unroll
        for (int j = 0; j < 8; j++) acc[j] += *(const f32x4*)(&kvs[f][e0 + 4 * j]) * p;
    }
    float rd = 1.f / den;
    __bf16* op = attn + row * 512 + hh * 64 + e0;
    #pragma unroll
    for (int j2 = 0; j2 < 4; j2++) {
        bf16x8 ov;
        #pragma unroll
        for (int k = 0; k < 8; k++) ov[k] = (__bf16)(acc[j2 * 2 + k / 4][k % 4] * rd);
        *(bf16x8*)(op + j2 * 8) = ov;
    }
}

extern "C" void kernel_launch(void* const* d_in, const int* in_sizes, int n_in,
                              void* d_out, int out_size, void* d_ws, size_t ws_size,
                              hipStream_t stream) {
    const int*   tokens = (const int*)d_in[0];
    const float* embed  = (const float*)d_in[1];
    const float* Wq     = (const float*)d_in[2];
    const float* Wk     = (const float*)d_in[3];
    const float* Wv     = (const float*)d_in[4];
    const float* Wo     = (const float*)d_in[5];
    const float* ln1_s  = (const float*)d_in[6];
    const float* ln1_b  = (const float*)d_in[7];
    const float* W1     = (const float*)d_in[8];
    const float* b1     = (const float*)d_in[9];
    const float* W2     = (const float*)d_in[10];
    const float* b2     = (const float*)d_in[11];
    const float* ln2_s  = (const float*)d_in[12];
    const float* ln2_b  = (const float*)d_in[13];
    const float* lnf_s  = (const float*)d_in[14];
    const float* lnf_b  = (const float*)d_in[15];
    float* out = (float*)d_out;

    float* ws = (float*)d_ws;
    size_t off = 0;
    float* pos = ws;               off += 2097152;            // 4096*512 f32
    float* x   = ws + off;         off += 8388608;            // 16384*512 f32
    __bf16* h    = (__bf16*)(ws + off); off += 4194304;       // 16384*512 bf16
    __bf16* attn = (__bf16*)(ws + off); off += 4194304;       // 16384*512 bf16
    __bf16* qkvb = (__bf16*)(ws + off);                       // 16384*1536 bf16
    __bf16* hid  = (__bf16*)(ws + off); off += 16777216;      // 16384*2048 bf16 (union, serialized)
    float* kvpart = ws + off;      off += 64 * 32 * 4160;     // partials (64 chunks)
    float* kvfin  = ws + off;      off += 32 * 4160;
    __bf16* wbuf  = (__bf16*)(ws + off);                      // 6 * 3145728 bf16

    pos_kernel<<<4096, 256, 0, stream>>>(pos);
    transpose_bf16<<<dim3(16, 16, 6), dim3(32, 8), 0, stream>>>(Wq, wbuf,          512, 512,  262144, 3145728);
    transpose_bf16<<<dim3(16, 16, 6), dim3(32, 8), 0, stream>>>(Wk, wbuf + 262144, 512, 512,  262144, 3145728);
    transpose_bf16<<<dim3(16, 16, 6), dim3(32, 8), 0, stream>>>(Wv, wbuf + 524288, 512, 512,  262144, 3145728);
    transpose_bf16<<<dim3(16, 16, 6), dim3(32, 8), 0, stream>>>(Wo, wbuf + 786432, 512, 512,  262144, 3145728);
    transpose_bf16<<<dim3(64, 16, 6), dim3(32, 8), 0, stream>>>(W1, wbuf + 1048576, 512, 2048, 1048576, 3145728);
    transpose_bf16<<<dim3(16, 64, 6), dim3(32, 8), 0, stream>>>(W2, wbuf + 2097152, 2048, 512, 1048576, 3145728);
    embed_kernel<<<16384, 128, 0, stream>>>(tokens, embed, pos, x);

    for (int l = 0; l < 6; l++) {
        const __bf16* wl = wbuf + (size_t)l * 3145728;
        ln_kernel<1><<<4096, 256, 0, stream>>>(x, ln1_s + l * 512, ln1_b + l * 512, h, nullptr);
        gemm_bt<1, 512><<<1536, 256, 0, stream>>>(h, wl, nullptr, qkvb, nullptr, 1536, 12);
        kv_partial<<<dim3(32, 64), 256, 0, stream>>>(qkvb, kvpart);
        kv_reduce<<<520, 256, 0, stream>>>(kvpart, kvfin);
        num_attn<<<dim3(32, 32), 256, 0, stream>>>(qkvb, kvfin, attn);
        gemm_bt<2, 512><<<512, 256, 0, stream>>>(attn, wl + 786432, x, nullptr, nullptr, 512, 4);
        ln_kernel<1><<<4096, 256, 0, stream>>>(x, ln2_s + l * 512, ln2_b + l * 512, h, nullptr);
        gemm_bt<3, 512><<<2048, 256, 0, stream>>>(h, wl + 1048576, nullptr, hid, b1 + (size_t)l * 2048, 2048, 16);
        gemm_bt<4, 2048><<<512, 256, 0, stream>>>(hid, wl + 2097152, x, nullptr, b2 + (size_t)l * 512, 512, 4);
    }
    ln_kernel<0><<<4096, 256, 0, stream>>>(x, lnf_s, lnf_b, nullptr, out);
}

// Round 6
// 1761.327 us; speedup vs baseline: 1.1870x; 1.0012x over previous
//
#include <hip/hip_runtime.h>

typedef float f32x4 __attribute__((ext_vector_type(4)));
typedef __bf16 bf16x8 __attribute__((ext_vector_type(8)));

#define NROWS 16384   // B*S
#define SEQ   4096
#define EMBD  512
#define MLPD  2048

__device__ inline float gelu_tanh(float x) {
    float t = 0.7978845608028654f * (x + 0.044715f * x * x * x);
    float e = __expf(2.f * t);
    float th = 1.f - 2.f / (1.f + e);
    return 0.5f * x * (1.f + th);
}

// direct global->LDS 16B DMA; LDS dest must be linear in lane order
#define GLOAD16(gp, lp)                                                        \
    __builtin_amdgcn_global_load_lds(                                          \
        (const __attribute__((address_space(1))) void*)(gp),                   \
        (__attribute__((address_space(3))) void*)(lp), 16, 0, 0)

// ---------------- positional table: pos[s][512] ----------------
__global__ void pos_kernel(float* __restrict__ pos) {
    int i = blockIdx.x * 256 + threadIdx.x;        // 4096*256
    int s = i >> 8, j = i & 255;
    float div = __expf((float)j * (-2.f * 9.210340371976184f / 512.f));
    float a = (float)s * div;
    pos[(size_t)s * 512 + 2 * j]     = sinf(a);
    pos[(size_t)s * 512 + 2 * j + 1] = cosf(a);
}

// ---------------- embedding gather + pos add ----------------
__global__ void embed_kernel(const int* __restrict__ tokens,
                             const float* __restrict__ embed,
                             const float* __restrict__ pos,
                             float* __restrict__ x) {
    int row = blockIdx.x;            // 16384
    int t = threadIdx.x;             // 128
    int s = row & (SEQ - 1);
    int tok = tokens[row];
    f32x4 e = *(const f32x4*)(embed + (size_t)tok * 512 + t * 4);
    f32x4 p = *(const f32x4*)(pos + (size_t)s * 512 + t * 4);
    e += p;
    *(f32x4*)(x + (size_t)row * 512 + t * 4) = e;
}

// ---------------- transpose fp32 [K][N] -> bf16 [N][K], batched over z ----------------
__global__ void transpose_bf16(const float* __restrict__ in, __bf16* __restrict__ out,
                               int K, int N, size_t in_lstride, size_t out_lstride) {
    __shared__ float tile[32][33];
    in  += (size_t)blockIdx.z * in_lstride;
    out += (size_t)blockIdx.z * out_lstride;
    int n0 = blockIdx.x * 32, k0 = blockIdx.y * 32;
    int tx = threadIdx.x, ty = threadIdx.y;   // 32 x 8
    #pragma unroll
    for (int i = 0; i < 32; i += 8)
        tile[ty + i][tx] = in[(size_t)(k0 + ty + i) * N + n0 + tx];
    __syncthreads();
    #pragma unroll
    for (int i = 0; i < 32; i += 8)
        out[(size_t)(n0 + ty + i) * K + k0 + tx] = (__bf16)tile[tx][ty + i];
}

// ---------------- LayerNorm (one wave per 512-row) ----------------
template<int OUTBF>
__global__ __launch_bounds__(256) void ln_kernel(
    const float* __restrict__ x, const float* __restrict__ gamma,
    const float* __restrict__ beta, __bf16* __restrict__ outb,
    float* __restrict__ outf) {
    int lane = threadIdx.x & 63;
    size_t row = (size_t)blockIdx.x * 4 + (threadIdx.x >> 6);
    const float* xr = x + row * 512 + lane * 8;
    f32x4 v0 = *(const f32x4*)xr;
    f32x4 v1 = *(const f32x4*)(xr + 4);
    float sum = (v0[0] + v0[1]) + (v0[2] + v0[3]) + (v1[0] + v1[1]) + (v1[2] + v1[3]);
    #pragma unroll
    for (int off = 32; off; off >>= 1) sum += __shfl_xor(sum, off);
    float mu = sum * (1.f / 512.f);
    float vs = 0.f;
    #pragma unroll
    for (int j = 0; j < 4; j++) {
        float d0 = v0[j] - mu; vs += d0 * d0;
        float d1 = v1[j] - mu; vs += d1 * d1;
    }
    #pragma unroll
    for (int off = 32; off; off >>= 1) vs += __shfl_xor(vs, off);
    float inv = rsqrtf(vs * (1.f / 512.f) + 1e-6f);
    const float* gp = gamma + lane * 8;
    const float* bp = beta + lane * 8;
    f32x4 g0 = *(const f32x4*)gp, g1 = *(const f32x4*)(gp + 4);
    f32x4 bb0 = *(const f32x4*)bp, bb1 = *(const f32x4*)(bp + 4);
    float o[8];
    #pragma unroll
    for (int j = 0; j < 4; j++) {
        o[j]     = (v0[j] - mu) * inv * g0[j] + bb0[j];
        o[4 + j] = (v1[j] - mu) * inv * g1[j] + bb1[j];
    }
    if (OUTBF) {
        bf16x8 ov;
        #pragma unroll
        for (int j = 0; j < 8; j++) ov[j] = (__bf16)o[j];
        *(bf16x8*)(outb + row * 512 + lane * 8) = ov;
    } else {
        f32x4 o0 = {o[0], o[1], o[2], o[3]};
        f32x4 o1 = {o[4], o[5], o[6], o[7]};
        *(f32x4*)(outf + row * 512 + lane * 8) = o0;
        *(f32x4*)(outf + row * 512 + lane * 8 + 4) = o1;
    }
}

// ---------------- MFMA GEMM: C[M,N] = A[M,K](bf16) @ BT[N,K](bf16) ----------------
// BM x 128 tile (BM = 128 or 64), BK=32, 3-slot LDS ring with 2-tile-ahead
// prefetch: issue tile s+2, wait vmcnt(2L) -> tiles s+1,s+2 stay in flight
// across the barrier while tile s computes (~2 compute phases of latency
// coverage). L = loads/thread/step = BM/64 + 2.
// WAR: tile s+2 reuses slot of s-1 whose reads finished before prev barrier.
// RAW: per-wave vmcnt before barrier -> all waves' loads resident after it.
// LDS swizzle: chunk ^= (row>>1)&3 on 64B rows; linear dest + pre-swizzled src.
// 1-D grid, bijective XCD-chunk swizzle, n-fastest for A-panel L2 reuse.
// EPI: 1 = qkv -> bf16 out, phi on cols<1024
//      2 = residual add into Cf
//      3 = +bias, gelu, bf16 out
//      4 = +bias, residual add into Cf
template<int EPI, int K, int BM>
__global__ __launch_bounds__(256, 4) void gemm_bt(
    const __bf16* __restrict__ A, const __bf16* __restrict__ BT,
    float* __restrict__ Cf, __bf16* __restrict__ Cb,
    const float* __restrict__ bias, int N, int nbn) {
    constexpr int NT = K / 32;
    constexpr int AL = BM / 64;            // A loads per thread per step
    constexpr int NREP = (BM == 128) ? 4 : 2;
    __shared__ __align__(16) __bf16 Asm[3][BM * 32];
    __shared__ __align__(16) __bf16 Bsm[3][128 * 32];
    const int t = threadIdx.x;
    const int lane = t & 63;
    const int wave = t >> 6;
    const int wr = (BM == 128) ? (wave >> 1) : 0;
    const int wc = (BM == 128) ? (wave & 1) : wave;
    const int nblk = gridDim.x;
    const int q = nblk >> 3, r = nblk & 7;
    const int xcd = blockIdx.x & 7, loc = blockIdx.x >> 3;
    const int swz = (xcd < r ? xcd * (q + 1) : r * (q + 1) + (xcd - r) * q) + loc;
    const int m0 = (swz / nbn) * BM, n0 = (swz % nbn) * 128;
    const int fr = lane & 15, fc = lane >> 4;

    // staging: BM*4 A-slots, 512 B-slots (16B each); pre-swizzled global chunk
    const __bf16* Aps[AL];
    const __bf16* Bps[2];
    int aslot[AL], bslot[2];
    #pragma unroll
    for (int j = 0; j < AL; j++) {
        int slot = t + 256 * j;
        int row = slot >> 2, cp = slot & 3;
        int sc = cp ^ ((row >> 1) & 3);
        Aps[j] = A + (size_t)(m0 + row) * K + sc * 8;
        aslot[j] = slot * 8;
    }
    #pragma unroll
    for (int j = 0; j < 2; j++) {
        int slot = t + 256 * j;
        int row = slot >> 2, cp = slot & 3;
        int sc = cp ^ ((row >> 1) & 3);
        Bps[j] = BT + (size_t)(n0 + row) * K + sc * 8;
        bslot[j] = slot * 8;
    }

    f32x4 acc[4][NREP];
    #pragma unroll
    for (int m = 0; m < 4; m++)
        #pragma unroll
        for (int n = 0; n < NREP; n++)
            acc[m][n] = (f32x4){0.f, 0.f, 0.f, 0.f};

    auto stage = [&](int koff, __bf16* Ad, __bf16* Bd) {
        #pragma unroll
        for (int j = 0; j < AL; j++) GLOAD16(Aps[j] + koff, Ad + aslot[j]);
        #pragma unroll
        for (int j = 0; j < 2; j++) GLOAD16(Bps[j] + koff, Bd + bslot[j]);
    };

    __bf16 *A0 = Asm[0], *A1 = Asm[1], *A2 = Asm[2];
    __bf16 *B0 = Bsm[0], *B1 = Bsm[1], *B2 = Bsm[2];
    stage(0, A0, B0);
    stage(32, A1, B1);

    for (int s = 0; s < NT; s++) {
        if (s + 2 < NT) {
            stage((s + 2) * 32, A2, B2);
            if constexpr (BM == 128) asm volatile("s_waitcnt vmcnt(8)" ::: "memory");
            else                     asm volatile("s_waitcnt vmcnt(6)" ::: "memory");
        } else if (s + 1 < NT) {
            if constexpr (BM == 128) asm volatile("s_waitcnt vmcnt(4)" ::: "memory");
            else                     asm volatile("s_waitcnt vmcnt(3)" ::: "memory");
        } else {
            asm volatile("s_waitcnt vmcnt(0)" ::: "memory");
        }
        __builtin_amdgcn_s_barrier();

        bf16x8 af[4], bfr[NREP];
        #pragma unroll
        for (int m = 0; m < 4; m++) {
            int ra = wr * 64 + m * 16 + fr;
            af[m] = *(const bf16x8*)(A0 + ra * 32 + ((fc ^ ((ra >> 1) & 3)) << 3));
        }
        #pragma unroll
        for (int n = 0; n < NREP; n++) {
            int rb = wc * (16 * NREP) + n * 16 + fr;
            bfr[n] = *(const bf16x8*)(B0 + rb * 32 + ((fc ^ ((rb >> 1) & 3)) << 3));
        }
        __builtin_amdgcn_s_setprio(1);
        #pragma unroll
        for (int m = 0; m < 4; m++)
            #pragma unroll
            for (int n = 0; n < NREP; n++)
                acc[m][n] = __builtin_amdgcn_mfma_f32_16x16x32_bf16(af[m], bfr[n], acc[m][n], 0, 0, 0);
        __builtin_amdgcn_s_setprio(0);
        __builtin_amdgcn_s_barrier();   // readers done before slot reuse

        __bf16* ta = A0; A0 = A1; A1 = A2; A2 = ta;
        __bf16* tb = B0; B0 = B1; B1 = B2; B2 = tb;
    }

    const int cr = (lane >> 4) * 4;
    const int cc = lane & 15;
    #pragma unroll
    for (int m = 0; m < 4; m++) {
        #pragma unroll
        for (int n = 0; n < NREP; n++) {
            #pragma unroll
            for (int r2 = 0; r2 < 4; r2++) {
                int grow = m0 + wr * 64 + m * 16 + cr + r2;
                int gcol = n0 + wc * (16 * NREP) + n * 16 + cc;
                size_t idx = (size_t)grow * N + gcol;
                float val = acc[m][n][r2];
                if (EPI == 1) {
                    if (gcol < 1024) val = fmaxf(val, 0.f) + 1e-3f;
                    Cb[idx] = (__bf16)val;
                } else if (EPI == 2) {
                    Cf[idx] += val;
                } else if (EPI == 3) {
                    val += bias[gcol];
                    Cb[idx] = (__bf16)gelu_tanh(val);
                } else if (EPI == 4) {
                    Cf[idx] += val + bias[gcol];
                } else {
                    Cf[idx] = val;
                }
            }
        }
    }
}

// ---------------- kv partial: per (b,h,chunk of 64 rows) 64x64 + pksum ----------------
__global__ __launch_bounds__(256) void kv_partial(const __bf16* __restrict__ qkvb,
                                                  float* __restrict__ part) {
    int bh = blockIdx.x;           // 32
    int chunk = blockIdx.y;        // 64 chunks of 64 rows
    int b = bh >> 3, hh = bh & 7;
    int t = threadIdx.x;
    int f = t & 63, eg = t >> 6;   // e-base = eg*16
    size_t base = ((size_t)b * SEQ + (size_t)chunk * 64) * 1536;
    const __bf16* kcol = qkvb + base + 512 + hh * 64 + f;
    const __bf16* vrow = qkvb + base + 1024 + hh * 64 + eg * 16;
    float psum = 0.f;
    f32x4 a0 = {0.f,0.f,0.f,0.f}, a1 = a0, a2 = a0, a3 = a0;
    for (int s = 0; s < 64; s++) {
        size_t o = (size_t)s * 1536;
        float pk = (float)kcol[o];
        psum += pk;
        bf16x8 w0 = *(const bf16x8*)(vrow + o);
        bf16x8 w1 = *(const bf16x8*)(vrow + o + 8);
        #pragma unroll
        for (int j = 0; j < 4; j++) {
            a0[j] += (float)w0[j]     * pk;
            a1[j] += (float)w0[4 + j] * pk;
            a2[j] += (float)w1[j]     * pk;
            a3[j] += (float)w1[4 + j] * pk;
        }
    }
    float* dst = part + ((size_t)chunk * 32 + bh) * 4160 + (size_t)f * 65 + eg * 16;
    #pragma unroll
    for (int j = 0; j < 4; j++) { dst[j] = a0[j]; dst[4+j] = a1[j]; dst[8+j] = a2[j]; dst[12+j] = a3[j]; }
    if (eg == 0) dst[64] = psum;   // pksum slot
}

__global__ void kv_reduce(const float* __restrict__ part, float* __restrict__ kvfin) {
    int i = blockIdx.x * 256 + threadIdx.x;
    if (i >= 32 * 4160) return;
    float s = 0.f;
    #pragma unroll 8
    for (int c = 0; c < 64; c++) s += part[(size_t)c * (32 * 4160) + i];
    kvfin[i] = s;
}

// ---------------- num / den / divide -> attn (bf16) ----------------
__global__ __launch_bounds__(256) void num_attn(const __bf16* __restrict__ qkvb,
                                                const float* __restrict__ kvfin,
                                                __bf16* __restrict__ attn) {
    __shared__ float kvs[64][68];
    __shared__ float ps[64];
    int bh = blockIdx.x, chunk = blockIdx.y;   // 32 x 32
    int b = bh >> 3, hh = bh & 7;
    const float* src = kvfin + (size_t)bh * 4160;
    for (int i = threadIdx.x; i < 4160; i += 256) {
        int f = i / 65, e = i - f * 65;
        if (e < 64) kvs[f][e] = src[i]; else ps[f] = src[i];
    }
    __syncthreads();
    int t = threadIdx.x;
    int r = t >> 1, e0 = (t & 1) * 32;
    size_t row = (size_t)b * SEQ + (size_t)chunk * 128 + r;
    const __bf16* pqr = qkvb + row * 1536 + hh * 64;
    float pq[64];
    #pragma unroll
    for (int j = 0; j < 8; j++) {
        bf16x8 v = *(const bf16x8*)(pqr + 8 * j);
        #pragma unroll
        for (int k = 0; k < 8; k++) pq[8 * j + k] = (float)v[k];
    }
    float den = 0.f;
    #pragma unroll
    for (int f = 0; f < 64; f++) den += pq[f] * ps[f];
    f32x4 acc[8];
    #pragma unroll
    for (int j = 0; j < 8; j++) acc[j] = (f32x4){0.f,0.f,0.f,0.f};
    for (int f = 0; f < 64; f++) {
        float p = pq[f];
        #pragma unroll
        for (int j = 0; j < 8; j++) acc[j] += *(const f32x4*)(&kvs[f][e0 + 4 * j]) * p;
    }
    float rd = 1.f / den;
    __bf16* op = attn + row * 512 + hh * 64 + e0;
    #pragma unroll
    for (int j2 = 0; j2 < 4; j2++) {
        bf16x8 ov;
        #pragma unroll
        for (int k = 0; k < 8; k++) ov[k] = (__bf16)(acc[j2 * 2 + k / 4][k % 4] * rd);
        *(bf16x8*)(op + j2 * 8) = ov;
    }
}

extern "C" void kernel_launch(void* const* d_in, const int* in_sizes, int n_in,
                              void* d_out, int out_size, void* d_ws, size_t ws_size,
                              hipStream_t stream) {
    const int*   tokens = (const int*)d_in[0];
    const float* embed  = (const float*)d_in[1];
    const float* Wq     = (const float*)d_in[2];
    const float* Wk     = (const float*)d_in[3];
    const float* Wv     = (const float*)d_in[4];
    const float* Wo     = (const float*)d_in[5];
    const float* ln1_s  = (const float*)d_in[6];
    const float* ln1_b  = (const float*)d_in[7];
    const float* W1     = (const float*)d_in[8];
    const float* b1     = (const float*)d_in[9];
    const float* W2     = (const float*)d_in[10];
    const float* b2     = (const float*)d_in[11];
    const float* ln2_s  = (const float*)d_in[12];
    const float* ln2_b  = (const float*)d_in[13];
    const float* lnf_s  = (const float*)d_in[14];
    const float* lnf_b  = (const float*)d_in[15];
    float* out = (float*)d_out;

    float* ws = (float*)d_ws;
    size_t off = 0;
    float* pos = ws;               off += 2097152;            // 4096*512 f32
    float* x   = ws + off;         off += 8388608;            // 16384*512 f32
    __bf16* h    = (__bf16*)(ws + off); off += 4194304;       // 16384*512 bf16
    __bf16* attn = (__bf16*)(ws + off); off += 4194304;       // 16384*512 bf16
    __bf16* qkvb = (__bf16*)(ws + off);                       // 16384*1536 bf16
    __bf16* hid  = (__bf16*)(ws + off); off += 16777216;      // 16384*2048 bf16 (union, serialized)
    float* kvpart = ws + off;      off += 64 * 32 * 4160;     // partials (64 chunks)
    float* kvfin  = ws + off;      off += 32 * 4160;
    __bf16* wbuf  = (__bf16*)(ws + off);                      // 6 * 3145728 bf16

    pos_kernel<<<4096, 256, 0, stream>>>(pos);
    transpose_bf16<<<dim3(16, 16, 6), dim3(32, 8), 0, stream>>>(Wq, wbuf,          512, 512,  262144, 3145728);
    transpose_bf16<<<dim3(16, 16, 6), dim3(32, 8), 0, stream>>>(Wk, wbuf + 262144, 512, 512,  262144, 3145728);
    transpose_bf16<<<dim3(16, 16, 6), dim3(32, 8), 0, stream>>>(Wv, wbuf + 524288, 512, 512,  262144, 3145728);
    transpose_bf16<<<dim3(16, 16, 6), dim3(32, 8), 0, stream>>>(Wo, wbuf + 786432, 512, 512,  262144, 3145728);
    transpose_bf16<<<dim3(64, 16, 6), dim3(32, 8), 0, stream>>>(W1, wbuf + 1048576, 512, 2048, 1048576, 3145728);
    transpose_bf16<<<dim3(16, 64, 6), dim3(32, 8), 0, stream>>>(W2, wbuf + 2097152, 2048, 512, 1048576, 3145728);
    embed_kernel<<<16384, 128, 0, stream>>>(tokens, embed, pos, x);

    for (int l = 0; l < 6; l++) {
        const __bf16* wl = wbuf + (size_t)l * 3145728;
        ln_kernel<1><<<4096, 256, 0, stream>>>(x, ln1_s + l * 512, ln1_b + l * 512, h, nullptr);
        gemm_bt<1, 512, 128><<<1536, 256, 0, stream>>>(h, wl, nullptr, qkvb, nullptr, 1536, 12);
        kv_partial<<<dim3(32, 64), 256, 0, stream>>>(qkvb, kvpart);
        kv_reduce<<<520, 256, 0, stream>>>(kvpart, kvfin);
        num_attn<<<dim3(32, 32), 256, 0, stream>>>(qkvb, kvfin, attn);
        gemm_bt<2, 512, 64><<<1024, 256, 0, stream>>>(attn, wl + 786432, x, nullptr, nullptr, 512, 4);
        ln_kernel<1><<<4096, 256, 0, stream>>>(x, ln2_s + l * 512, ln2_b + l * 512, h, nullptr);
        gemm_bt<3, 512, 128><<<2048, 256, 0, stream>>>(h, wl + 1048576, nullptr, hid, b1 + (size_t)l * 2048, 2048, 16);
        gemm_bt<4, 2048, 64><<<1024, 256, 0, stream>>>(hid, wl + 2097152, x, nullptr, b2 + (size_t)l * 512, 512, 4);
    }
    ln_kernel<0><<<4096, 256, 0, stream>>>(x, lnf_s, lnf_b, nullptr, out);
}